// Round 9
// baseline (326.162 us; speedup 1.0000x reference)
//
#include <hip/hip_runtime.h>
#include <math.h>

// ---------------------------------------------------------------------------
// FraudDetectionGCN: 3x GCNConv(relu) + FC + log_softmax.
// R23 changes vs R22 (263.5 us, regression) / R20 (233.6 us, best):
//  * CSR/perm plumbing reverted to R20 exactly (R22's perm indirection cost
//    +11.6MB RMW fetch on g2 writes + a serial dependency level).
//  * gather rewritten: ONE NODE PER WAVE. lane = 8*e + o: edge-slot e in
//    [0,8) x feature-octet o in [0,8) (16B dwordx4 per lane). The edge loop
//    is wave-uniform -> zero exec-mask waste, no max-over-groups (R19/R21/
//    R22 all showed intra-wave degree structure is the cost). col read is
//    one coalesced 32B broadcast; addr math amortized over 8 edges; end of
//    node folds edge-slots with 3 shfl_xor rounds (stride 8/16/32).
//  * agg_lin: 1024-thr block = 16 waves = 16 nodes; R20 MFMA epilogue
//    verbatim on waves 0-3. __launch_bounds__(1024,8) pins VGPR<=64 for
//    2 blocks/CU (32 waves).
//  * agg_final: 256-thr block = 4 nodes; 8-float Wfc slice, o-reduce 1/2/4.
// agg: bf16 g rows; norm factorization:
// out[n] = dinv[n]*(sum_{s->n} g[s] + g[n]) + b, g = dinv[:,None]*(h@W).
// ---------------------------------------------------------------------------

static inline size_t alignup(size_t x){ return (x + 511) & ~size_t(511); }

typedef float v4f __attribute__((ext_vector_type(4)));
typedef unsigned short v4u16 __attribute__((ext_vector_type(4)));
typedef unsigned short v8u16 __attribute__((ext_vector_type(8)));
typedef __attribute__((ext_vector_type(8))) short short8;   // MFMA A/B frag (8 bf16)
typedef __attribute__((ext_vector_type(4))) float f32x4;    // MFMA C/D frag

__device__ __forceinline__ unsigned short f32_to_bf16(float f){
  union { float f; unsigned int u; } c; c.f = f;
  unsigned int u = c.u + 0x7FFFu + ((c.u >> 16) & 1u);   // round-nearest-even
  return (unsigned short)(u >> 16);
}
__device__ __forceinline__ v4f bf16x4_to_f32(v4u16 a){
  union { unsigned int u; float f; } c0,c1,c2,c3;
  c0.u = (unsigned int)a.x << 16;
  c1.u = (unsigned int)a.y << 16;
  c2.u = (unsigned int)a.z << 16;
  c3.u = (unsigned int)a.w << 16;
  v4f r; r.x=c0.f; r.y=c1.f; r.z=c2.f; r.w=c3.f;
  return r;
}
__device__ __forceinline__ v4f bf16lo(v8u16 r){
  v4u16 t; t.x=r[0]; t.y=r[1]; t.z=r[2]; t.w=r[3]; return bf16x4_to_f32(t);
}
__device__ __forceinline__ v4f bf16hi(v8u16 r){
  v4u16 t; t.x=r[4]; t.y=r[5]; t.z=r[6]; t.w=r[7]; return bf16x4_to_f32(t);
}
__device__ __forceinline__ v4f shflxor4(v4f v, int m){
  v4f r;
  r.x = __shfl_xor(v.x, m, 64);
  r.y = __shfl_xor(v.y, m, 64);
  r.z = __shfl_xor(v.z, m, 64);
  r.w = __shfl_xor(v.w, m, 64);
  return r;
}

#define NBUCK 1024          // histogram bins (dst>>7); 782 used at N=100k
#define CHUNK 8192          // edges per block in scatter (196 blocks)
#define CCAP  3584          // bucket region stride (mean ~2046, +34 sigma)

// Build one bf16 MFMA B-fragment entry for W[ksteps*32][64]:
// wf[ks][nb][lane][i] = bf16( W[ks*32 + 8*(lane>>4) + i][nb*16 + (lane&15)] ).
__device__ __forceinline__ void wfrag_one(const float* __restrict__ W,
                                          unsigned short* __restrict__ wf,
                                          int idx, int ksteps){
  int total = ksteps*4*64;
  if(idx >= total) return;
  int l  = idx & 63;
  int nb = (idx>>6) & 3;
  int ks = idx>>8;
  int k0 = ks*32 + 8*(l>>4);
  int n  = nb*16 + (l&15);
  unsigned short* o = wf + (size_t)idx*8;
  #pragma unroll
  for(int i=0;i<8;i++) o[i] = f32_to_bf16(W[(size_t)(k0+i)*64 + n]);
}

// One-shot setup: W1/W2/W3 fragments, zero bfill, zero g zero-rows. 8 blocks.
__global__ __launch_bounds__(256) void setup_kernel(const float* __restrict__ W1,
                                                    const float* __restrict__ W2,
                                                    const float* __restrict__ W3,
                                                    unsigned short* __restrict__ wf1,
                                                    unsigned short* __restrict__ wf2,
                                                    unsigned short* __restrict__ wf3,
                                                    int* __restrict__ bfill,
                                                    unsigned short* __restrict__ gAz,
                                                    unsigned short* __restrict__ gBz){
  int b = blockIdx.x, t = threadIdx.x;
  if(b < 4)      wfrag_one(W1, wf1, b*256+t, 4);
  else if(b < 6) wfrag_one(W2, wf2, (b-4)*256+t, 2);
  else           wfrag_one(W3, wf3, (b-6)*256+t, 2);
  if(b < 4) bfill[b*256+t] = 0;                 // 1024 bucket counters
  if(b==4 && t<32) ((int*)gAz)[t] = 0;          // zero row (64 bf16 = 32 ints)
  if(b==5 && t<32) ((int*)gBz)[t] = 0;
}

// Scatter packed (local_dst<<17 | src) into fixed-stride bucket regions,
// LDS-presorted so global writes are dense runs. 1024 threads (16 waves).
// Bucket base is b*CCAP (compile-time stride): no hist/scan passes needed.
__global__ __launch_bounds__(1024) void scatter_kernel(const int* __restrict__ src,
                                                       const int* __restrict__ dst,
                                                       int* __restrict__ bfill,
                                                       int* __restrict__ pairs, int E){
  __shared__ int hist[NBUCK];            // counts -> reused as fill counters
  __shared__ int delta[NBUCK];           // gstart - lstart per bucket
  __shared__ int wsum[16];
  __shared__ int vals[CHUNK];            // 32KB sorted-by-bucket payloads
  __shared__ unsigned short bkt[CHUNK];  // 16KB bucket id per slot
  int t = threadIdx.x;
  int lane = t & 63, wid = t >> 6;
  int cbase = blockIdx.x*CHUNK;
  hist[t]=0;                             // NBUCK == 1024
  __syncthreads();
  // A: local histogram
  #pragma unroll
  for(int i=0;i<CHUNK;i+=1024){
    int e = cbase+i+t;
    if(e<E) atomicAdd(&hist[dst[e]>>7], 1);
  }
  __syncthreads();
  // B: block-exclusive scan (1 bucket/thread): wave shfl scan + combine
  int v = hist[t];
  int x = v;
  #pragma unroll
  for(int off=1; off<64; off<<=1){
    int y = __shfl_up(x, off, 64);
    if(lane >= off) x += y;
  }
  if(lane==63) wsum[wid]=x;
  __syncthreads();
  if(wid==0){
    int s2 = (lane<16) ? wsum[lane] : 0;
    #pragma unroll
    for(int off=1; off<16; off<<=1){
      int y = __shfl_up(s2, off, 64);
      if(lane >= off) s2 += y;
    }
    if(lane<16) wsum[lane]=s2;
  }
  __syncthreads();
  int run = (x - v) + (wid ? wsum[wid-1] : 0);      // exclusive local start
  int g = v ? atomicAdd(&bfill[t], v) : 0;          // reserve in bucket region
  hist[t]=run; delta[t]= t*CCAP + g - run;          // hist becomes fill counter
  __syncthreads();
  // C: place into LDS sorted by bucket
  #pragma unroll
  for(int i=0;i<CHUNK;i+=1024){
    int e = cbase+i+t;
    if(e<E){
      int d = dst[e];
      int b = d>>7;
      int slot = atomicAdd(&hist[b], 1);
      vals[slot] = ((d&127)<<17) | src[e];
      bkt[slot]  = (unsigned short)b;
    }
  }
  __syncthreads();
  // D: dense copy-out (addresses consecutive within each run)
  int cnt = E - cbase; if(cnt > CHUNK) cnt = CHUNK;
  for(int i=t;i<cnt;i+=1024){
    int b = bkt[i];
    pairs[delta[b] + i] = vals[i];
  }
}

// One block per bucket (128 dst nodes). LDS counting sort -> rowse {s,e},
// dinv, srcs staged in LDS -> fully-contiguous col writes. (R20 form.)
__global__ __launch_bounds__(256) void bucket_csr_kernel(const int* __restrict__ pairs,
                                                         const int* __restrict__ bfill,
                                                         int2* __restrict__ rowse,
                                                         float* __restrict__ dinv,
                                                         int* __restrict__ col,
                                                         int N){
  __shared__ int hist[128];
  __shared__ int pref[128];
  __shared__ int fill[128];
  __shared__ int srcs[CCAP];
  int b = blockIdx.x, t = threadIdx.x;
  int s0 = b*CCAP;
  int cnt = bfill[b]; if(cnt > CCAP) cnt = CCAP;   // unreachable guard
  if(t<128) hist[t]=0;
  __syncthreads();
  int v[CCAP/256];
  #pragma unroll
  for(int i=0;i<CCAP/256;i++){
    int idx = i*256 + t;
    if(idx<cnt){ v[i]=pairs[s0+idx]; atomicAdd(&hist[v[i]>>17], 1); }
  }
  __syncthreads();
  if(t<128) pref[t]=hist[t];
  __syncthreads();
  for(int off=1; off<128; off<<=1){
    int x=0;
    if(t<128 && t>=off) x=pref[t-off];
    __syncthreads();
    if(t<128) pref[t]+=x;
    __syncthreads();
  }
  if(t<128){
    int ex = pref[t]-hist[t];                 // exclusive prefix
    fill[t]=ex;
    int node = b*128 + t;
    if(node<N){
      rowse[node] = make_int2(s0+ex, s0+ex+hist[t]);
      dinv[node] = rsqrtf((float)(hist[t]+1)); // +1 self loop
    }
  }
  __syncthreads();
  #pragma unroll
  for(int i=0;i<CCAP/256;i++){
    int idx = i*256 + t;
    if(idx<cnt){
      int ld = v[i]>>17;
      int pos = atomicAdd(&fill[ld], 1);
      srcs[pos] = v[i] & 0x1FFFF;
    }
  }
  __syncthreads();
  for(int i=t;i<cnt;i+=256) col[s0+i]=srcs[i];   // contiguous
}

// g[n,:] = bf16( dinv[n] * (x[n,:128] @ W1[128,64]) ) via MFMA 16x16x32 bf16.
// Block = 64 rows (4 waves x 16 rows), 16 MFMAs/wave (4 ksteps x 4 nblocks).
// A-frags from global (lane l: row l&15, k-octet 8*(l>>4)); B-frags from LDS.
__global__ __launch_bounds__(256) void lin_mfma_kernel(const float* __restrict__ x,
                                                       const unsigned short* __restrict__ wf,
                                                       const float* __restrict__ dinv,
                                                       unsigned short* __restrict__ g,
                                                       int N){
  __shared__ __align__(16) unsigned short wl[4*4*64*8];   // 16KB
  int t = threadIdx.x, wave = t>>6, lane = t&63;
  #pragma unroll
  for(int idx=t; idx<1024; idx+=256)
    ((v4f*)wl)[idx] = ((const v4f*)wf)[idx];              // 16B per entry
  __syncthreads();
  int row = blockIdx.x*64 + wave*16 + (lane&15);
  int arow = row < N ? row : N-1;
  const float* xr = x + (size_t)arow*128 + 8*(lane>>4);
  f32x4 acc0={0.f,0.f,0.f,0.f}, acc1=acc0, acc2=acc0, acc3=acc0;
  #pragma unroll
  for(int ks=0; ks<4; ks++){
    v4f a0 = *(const v4f*)(xr + ks*32);
    v4f a1 = *(const v4f*)(xr + ks*32 + 4);
    short8 af;
    af[0]=(short)f32_to_bf16(a0.x); af[1]=(short)f32_to_bf16(a0.y);
    af[2]=(short)f32_to_bf16(a0.z); af[3]=(short)f32_to_bf16(a0.w);
    af[4]=(short)f32_to_bf16(a1.x); af[5]=(short)f32_to_bf16(a1.y);
    af[6]=(short)f32_to_bf16(a1.z); af[7]=(short)f32_to_bf16(a1.w);
    const short8* wb = ((const short8*)wl) + ks*256 + lane;
    acc0 = __builtin_amdgcn_mfma_f32_16x16x32_bf16(af, wb[0],   acc0, 0, 0, 0);
    acc1 = __builtin_amdgcn_mfma_f32_16x16x32_bf16(af, wb[64],  acc1, 0, 0, 0);
    acc2 = __builtin_amdgcn_mfma_f32_16x16x32_bf16(af, wb[128], acc2, 0, 0, 0);
    acc3 = __builtin_amdgcn_mfma_f32_16x16x32_bf16(af, wb[192], acc3, 0, 0, 0);
  }
  // C layout (m89-verified): col = lane&15, row = (lane>>4)*4 + j.
  int rbase = blockIdx.x*64 + wave*16 + (lane>>4)*4;
  int c = lane & 15;
  #pragma unroll
  for(int j=0;j<4;j++){
    int r = rbase + j;
    if(r < N){
      float dv = dinv[r];
      unsigned short* go = g + (size_t)r*64 + c;
      go[0]  = f32_to_bf16(dv*acc0[j]);
      go[16] = f32_to_bf16(dv*acc1[j]);
      go[32] = f32_to_bf16(dv*acc2[j]);
      go[48] = f32_to_bf16(dv*acc3[j]);
    }
  }
}

// One-node-per-wave gather. lane = 8*es + o: edge-slot es in [0,8), feature
// octet o in [0,8) (16B dwordx4 of the 128B row per lane). Edge loop is
// wave-uniform (no exec-mask waste); masked slots clamp to zeroed row ZR.
// After the loop, shfl_xor strides 8/16/32 fold the 8 edge-slots; ALL lanes
// then hold the full sums for their o.
__device__ __forceinline__ void gather_node(const unsigned short* __restrict__ g,
                                            const int* __restrict__ col,
                                            int n, int s, int e, int es, int o, int ZR,
                                            v4f& accA, v4f& accB){
  v8u16 sr = *(const v8u16*)&g[(size_t)n*64 + o*8];    // self slice
  v4f z = {0.f,0.f,0.f,0.f};
  accA = (es==0) ? bf16lo(sr) : z;
  accB = (es==0) ? bf16hi(sr) : z;
  for(int i = s; i < e; i += 8){
    int rem = e - i;                                   // wave-uniform
    int c = (es < rem) ? col[i + es] : ZR;             // coalesced 32B + clamp
    v8u16 x = *(const v8u16*)&g[(size_t)c*64 + o*8];
    accA = accA + bf16lo(x);
    accB = accB + bf16hi(x);
  }
  #pragma unroll
  for(int st=8; st<64; st<<=1){
    accA = accA + shflxor4(accA, st);
    accB = accB + shflxor4(accB, st);
  }
}

// Fused agg + next-layer linear. Block = 1024 thr = 16 waves = 16 nodes.
// h = relu(dinv*gather + b) -> bf16 rows in LDS (144B pitch), then
// h[16x64] @ W[64x64] via 8 MFMAs on waves 0-3 (R20 epilogue verbatim).
__global__ __launch_bounds__(1024, 8) void agg_lin_kernel(const unsigned short* __restrict__ g,
                                                          const int2* __restrict__ rowse,
                                                          const int* __restrict__ col,
                                                          const float* __restrict__ dinv,
                                                          const float* __restrict__ bias,
                                                          const unsigned short* __restrict__ wf,
                                                          unsigned short* __restrict__ g2,
                                                          int N){
  __shared__ __align__(16) unsigned short hsh[16*72];     // 2.25KB padded bf16 h
  __shared__ __align__(16) unsigned short wl[2*4*64*8];   // 8KB W frags
  int t = threadIdx.x, wave = t>>6, lane = t&63;
  int es = lane >> 3, o = lane & 7;
  // stage W frags once per block: 512 x 16B, coalesced
  if(t < 512) ((v4f*)wl)[t] = ((const v4f*)wf)[t];
  int base = blockIdx.x*16;
  int n = base + wave;
  int nn = n < N ? n : N-1;
  int2 se = rowse[nn];
  v4f aA, aB;
  gather_node(g, col, nn, se.x, se.y, es, o, N, aA, aB);
  float dv = dinv[nn];
  v4f b0 = *(const v4f*)&bias[o*8];
  v4f b1 = *(const v4f*)&bias[o*8+4];
  if(es == 0){                                          // lanes 0-7 write h row
    v8u16 hb;
    hb[0] = f32_to_bf16(fmaxf(fmaf(dv, aA.x, b0.x), 0.f));
    hb[1] = f32_to_bf16(fmaxf(fmaf(dv, aA.y, b0.y), 0.f));
    hb[2] = f32_to_bf16(fmaxf(fmaf(dv, aA.z, b0.z), 0.f));
    hb[3] = f32_to_bf16(fmaxf(fmaf(dv, aA.w, b0.w), 0.f));
    hb[4] = f32_to_bf16(fmaxf(fmaf(dv, aB.x, b1.x), 0.f));
    hb[5] = f32_to_bf16(fmaxf(fmaf(dv, aB.y, b1.y), 0.f));
    hb[6] = f32_to_bf16(fmaxf(fmaf(dv, aB.z, b1.z), 0.f));
    hb[7] = f32_to_bf16(fmaxf(fmaf(dv, aB.w, b1.w), 0.f));
    *(v8u16*)&hsh[wave*72 + o*8] = hb;
  }
  __syncthreads();
  if(wave >= 4) return;
  // ---- h @ W via MFMA; wave = col-block nb (R20 epilogue) ----
  short8 a0 = *(const short8*)&hsh[(lane&15)*72 +      8*(lane>>4)];
  short8 a1 = *(const short8*)&hsh[(lane&15)*72 + 32 + 8*(lane>>4)];
  const short8* wb = ((const short8*)wl) + wave*64 + lane;
  f32x4 oc = {0.f,0.f,0.f,0.f};
  oc = __builtin_amdgcn_mfma_f32_16x16x32_bf16(a0, wb[0],   oc, 0, 0, 0);
  oc = __builtin_amdgcn_mfma_f32_16x16x32_bf16(a1, wb[256], oc, 0, 0, 0);
  // C layout: col = lane&15, row = (lane>>4)*4 + j
  int c  = wave*16 + (lane&15);
  int r0 = base + (lane>>4)*4;
  #pragma unroll
  for(int j=0;j<4;j++){
    int r = r0 + j;
    if(r < N)
      g2[(size_t)r*64 + c] = f32_to_bf16(dinv[r]*oc[j]);
  }
}

// Layer-3 agg with fused FC + log_softmax epilogue. One node per wave
// (4 nodes per 256-thr block); Wfc slice = 16 floats per o; reduce over o.
__global__ __launch_bounds__(256) void agg_final_kernel(const unsigned short* __restrict__ g,
                                                        const int2* __restrict__ rowse,
                                                        const int* __restrict__ col,
                                                        const float* __restrict__ dinv,
                                                        const float* __restrict__ bias,
                                                        const float* __restrict__ Wfc,
                                                        const float* __restrict__ bfc,
                                                        float* __restrict__ out, int N){
  int t = threadIdx.x, wave = t>>6, lane = t&63;
  int es = lane >> 3, o = lane & 7;
  int n = blockIdx.x*4 + wave;
  bool valid = n < N;
  if(!valid) n = N-1;
  int2 se = rowse[n];
  v4f aA, aB;
  gather_node(g, col, n, se.x, se.y, es, o, N, aA, aB);
  float dv = dinv[n];
  v4f b0 = *(const v4f*)&bias[o*8];
  v4f b1 = *(const v4f*)&bias[o*8+4];
  v4f hA, hB;
  hA.x = fmaxf(fmaf(dv, aA.x, b0.x), 0.f);
  hA.y = fmaxf(fmaf(dv, aA.y, b0.y), 0.f);
  hA.z = fmaxf(fmaf(dv, aA.z, b0.z), 0.f);
  hA.w = fmaxf(fmaf(dv, aA.w, b0.w), 0.f);
  hB.x = fmaxf(fmaf(dv, aB.x, b1.x), 0.f);
  hB.y = fmaxf(fmaf(dv, aB.y, b1.y), 0.f);
  hB.z = fmaxf(fmaf(dv, aB.z, b1.z), 0.f);
  hB.w = fmaxf(fmaf(dv, aB.w, b1.w), 0.f);
  // Wfc row-major [64][2]: octet o covers rows 8o..8o+7 -> 16 floats at 16o.
  v4f wa = *(const v4f*)&Wfc[o*16];
  v4f wb = *(const v4f*)&Wfc[o*16+4];
  v4f wc = *(const v4f*)&Wfc[o*16+8];
  v4f wd = *(const v4f*)&Wfc[o*16+12];
  float p0 = hA.x*wa.x + hA.y*wa.z + hA.z*wb.x + hA.w*wb.z
           + hB.x*wc.x + hB.y*wc.z + hB.z*wd.x + hB.w*wd.z;
  float p1 = hA.x*wa.y + hA.y*wa.w + hA.z*wb.y + hA.w*wb.w
           + hB.x*wc.y + hB.y*wc.w + hB.z*wd.y + hB.w*wd.w;
  #pragma unroll
  for(int off=1; off<8; off<<=1){                 // reduce over o
    p0 += __shfl_xor(p0, off, 64);
    p1 += __shfl_xor(p1, off, 64);
  }
  if(valid && lane==0){
    float l0 = p0 + bfc[0], l1 = p1 + bfc[1];
    float m  = fmaxf(l0, l1);
    float lse = m + logf(expf(l0-m) + expf(l1-m));
    out[(size_t)n*2+0] = l0 - lse;
    out[(size_t)n*2+1] = l1 - lse;
  }
}

extern "C" void kernel_launch(void* const* d_in, const int* in_sizes, int n_in,
                              void* d_out, int out_size, void* d_ws, size_t ws_size,
                              hipStream_t stream) {
  (void)n_in; (void)out_size; (void)ws_size;
  const float* x   = (const float*)d_in[0];
  const int*   ei  = (const int*)  d_in[1];
  const float* W1  = (const float*)d_in[2];
  const float* b1  = (const float*)d_in[3];
  const float* W2  = (const float*)d_in[4];
  const float* b2  = (const float*)d_in[5];
  const float* W3  = (const float*)d_in[6];
  const float* b3  = (const float*)d_in[7];
  const float* Wfc = (const float*)d_in[8];
  const float* bfc = (const float*)d_in[9];
  float* out = (float*)d_out;

  const int N = in_sizes[0] / 128;   // 100000
  const int E = in_sizes[1] / 2;     // 1600000
  const int* src = ei;
  const int* dst = ei + E;
  const int NB = (N + 127) / 128;    // 782 buckets

  // ---- workspace carve ----
  char* w = (char*)d_ws;
  int*   bfill   = (int*)  w; w += alignup((size_t)NBUCK*4);
  int*   pairs   = (int*)  w; w += alignup((size_t)NBUCK*CCAP*4);   // 14.7MB strided
  int2*  rowse   = (int2*) w; w += alignup((size_t)N*8);
  float* dinv    = (float*)w; w += alignup((size_t)N*4);
  int*   col     = (int*)  w; w += alignup((size_t)NBUCK*CCAP*4);   // 14.7MB strided
  unsigned short* gA = (unsigned short*)w; w += alignup((size_t)(N+1)*64*2); // bf16 (+zero row)
  unsigned short* gB = (unsigned short*)w; w += alignup((size_t)(N+1)*64*2); // bf16 (+zero row)
  unsigned short* wf1 = (unsigned short*)w; w += alignup((size_t)4*4*64*8*2); // W1 frags 16KB
  unsigned short* wf2 = (unsigned short*)w; w += alignup((size_t)2*4*64*8*2); // W2 frags 8KB
  unsigned short* wf3 = (unsigned short*)w; w += alignup((size_t)2*4*64*8*2); // W3 frags 8KB

  const int nblkE    = (E + CHUNK - 1) / CHUNK;  // 196
  const int nblkLin  = (N + 63) / 64;            // 64 rows per MFMA block
  const int nblkAggL = (N + 15) / 16;            // 16 nodes/block (1024 thr)
  const int nblkAggF = (N + 3) / 4;              // 4 nodes/block (256 thr)

  // ---- setup (one kernel): W frags + bfill zero + g zero-rows ----
  setup_kernel<<<8, 256, 0, stream>>>(W1, W2, W3, wf1, wf2, wf3, bfill,
                                      gA + (size_t)N*64, gB + (size_t)N*64);
  // ---- CSR build: scatter into fixed-stride buckets, then per-bucket sort ----
  scatter_kernel<<<nblkE, 1024, 0, stream>>>(src, dst, bfill, pairs, E);
  bucket_csr_kernel<<<NB, 256, 0, stream>>>(pairs, bfill, rowse, dinv, col, N);

  // ---- layer 1 linear via MFMA: x[N,128] -> gA ----
  lin_mfma_kernel<<<nblkLin, 256, 0, stream>>>(x, wf1, dinv, gA, N);
  // ---- agg1 + lin2 fused (MFMA epilogue): gA -> gB ----
  agg_lin_kernel<<<nblkAggL, 1024, 0, stream>>>(gA, rowse, col, dinv, b1, wf2, gB, N);
  // ---- agg2 + lin3 fused (MFMA epilogue): gB -> gA ----
  agg_lin_kernel<<<nblkAggL, 1024, 0, stream>>>(gB, rowse, col, dinv, b2, wf3, gA, N);
  // ---- agg3 + FC + log_softmax (fused): gA -> out ----
  agg_final_kernel<<<nblkAggF, 256, 0, stream>>>(gA, rowse, col, dinv, b3,
                                                 Wfc, bfc, out, N);
}

// Round 10
// 278.808 us; speedup vs baseline: 1.1698x; 1.1698x over previous
//
#include <hip/hip_runtime.h>
#include <math.h>

// ---------------------------------------------------------------------------
// FraudDetectionGCN: 3x GCNConv(relu) + FC + log_softmax.
// R24 changes vs R23 (326 us, regression) / R20 (233.6 us, best):
//  * Full revert to R20 (agg/CSR/lin paths byte-identical). R19/R21/R22/R23
//    all showed R20's gather (16-lane groups, 4-granular early-break) is the
//    execution-structure optimum; agg time tracks FETCH_SIZE/~2TB/s.
//  * ONE new change: bucket_csr sorts each node's neighbor list by src id
//    (128 parallel LDS insertion sorts, one thread/node). Sorted lists make
//    all concurrent waves sweep the g-table in near-lockstep -> instantaneous
//    working set ~1-2MB fits per-XCD L2 -> fewer random-row L2 misses.
//    (Summation order change is legal: placement order was already
//    nondeterministic via atomicAdd; within bf16 noise.)
// agg: bf16 g rows; norm factorization:
// out[n] = dinv[n]*(sum_{s->n} g[s] + g[n]) + b, g = dinv[:,None]*(h@W).
// ---------------------------------------------------------------------------

static inline size_t alignup(size_t x){ return (x + 511) & ~size_t(511); }

typedef float v4f __attribute__((ext_vector_type(4)));
typedef unsigned short v4u16 __attribute__((ext_vector_type(4)));
typedef __attribute__((ext_vector_type(8))) short short8;   // MFMA A/B frag (8 bf16)
typedef __attribute__((ext_vector_type(4))) float f32x4;    // MFMA C/D frag

__device__ __forceinline__ unsigned short f32_to_bf16(float f){
  union { float f; unsigned int u; } c; c.f = f;
  unsigned int u = c.u + 0x7FFFu + ((c.u >> 16) & 1u);   // round-nearest-even
  return (unsigned short)(u >> 16);
}
__device__ __forceinline__ v4f bf16x4_to_f32(v4u16 a){
  union { unsigned int u; float f; } c0,c1,c2,c3;
  c0.u = (unsigned int)a.x << 16;
  c1.u = (unsigned int)a.y << 16;
  c2.u = (unsigned int)a.z << 16;
  c3.u = (unsigned int)a.w << 16;
  v4f r; r.x=c0.f; r.y=c1.f; r.z=c2.f; r.w=c3.f;
  return r;
}

#define NBUCK 1024          // histogram bins (dst>>7); 782 used at N=100k
#define CHUNK 8192          // edges per block in scatter (196 blocks)
#define CCAP  3584          // bucket region stride (mean ~2046, +34 sigma)

// Build one bf16 MFMA B-fragment entry for W[ksteps*32][64]:
// wf[ks][nb][lane][i] = bf16( W[ks*32 + 8*(lane>>4) + i][nb*16 + (lane&15)] ).
__device__ __forceinline__ void wfrag_one(const float* __restrict__ W,
                                          unsigned short* __restrict__ wf,
                                          int idx, int ksteps){
  int total = ksteps*4*64;
  if(idx >= total) return;
  int l  = idx & 63;
  int nb = (idx>>6) & 3;
  int ks = idx>>8;
  int k0 = ks*32 + 8*(l>>4);
  int n  = nb*16 + (l&15);
  unsigned short* o = wf + (size_t)idx*8;
  #pragma unroll
  for(int i=0;i<8;i++) o[i] = f32_to_bf16(W[(size_t)(k0+i)*64 + n]);
}

// One-shot setup: W1/W2/W3 fragments, zero bfill, zero g zero-rows. 8 blocks.
__global__ __launch_bounds__(256) void setup_kernel(const float* __restrict__ W1,
                                                    const float* __restrict__ W2,
                                                    const float* __restrict__ W3,
                                                    unsigned short* __restrict__ wf1,
                                                    unsigned short* __restrict__ wf2,
                                                    unsigned short* __restrict__ wf3,
                                                    int* __restrict__ bfill,
                                                    unsigned short* __restrict__ gAz,
                                                    unsigned short* __restrict__ gBz){
  int b = blockIdx.x, t = threadIdx.x;
  if(b < 4)      wfrag_one(W1, wf1, b*256+t, 4);
  else if(b < 6) wfrag_one(W2, wf2, (b-4)*256+t, 2);
  else           wfrag_one(W3, wf3, (b-6)*256+t, 2);
  if(b < 4) bfill[b*256+t] = 0;                 // 1024 bucket counters
  if(b==4 && t<32) ((int*)gAz)[t] = 0;          // zero row (64 bf16 = 32 ints)
  if(b==5 && t<32) ((int*)gBz)[t] = 0;
}

// Scatter packed (local_dst<<17 | src) into fixed-stride bucket regions,
// LDS-presorted so global writes are dense runs. 1024 threads (16 waves).
// Bucket base is b*CCAP (compile-time stride): no hist/scan passes needed.
__global__ __launch_bounds__(1024) void scatter_kernel(const int* __restrict__ src,
                                                       const int* __restrict__ dst,
                                                       int* __restrict__ bfill,
                                                       int* __restrict__ pairs, int E){
  __shared__ int hist[NBUCK];            // counts -> reused as fill counters
  __shared__ int delta[NBUCK];           // gstart - lstart per bucket
  __shared__ int wsum[16];
  __shared__ int vals[CHUNK];            // 32KB sorted-by-bucket payloads
  __shared__ unsigned short bkt[CHUNK];  // 16KB bucket id per slot
  int t = threadIdx.x;
  int lane = t & 63, wid = t >> 6;
  int cbase = blockIdx.x*CHUNK;
  hist[t]=0;                             // NBUCK == 1024
  __syncthreads();
  // A: local histogram
  #pragma unroll
  for(int i=0;i<CHUNK;i+=1024){
    int e = cbase+i+t;
    if(e<E) atomicAdd(&hist[dst[e]>>7], 1);
  }
  __syncthreads();
  // B: block-exclusive scan (1 bucket/thread): wave shfl scan + combine
  int v = hist[t];
  int x = v;
  #pragma unroll
  for(int off=1; off<64; off<<=1){
    int y = __shfl_up(x, off, 64);
    if(lane >= off) x += y;
  }
  if(lane==63) wsum[wid]=x;
  __syncthreads();
  if(wid==0){
    int s2 = (lane<16) ? wsum[lane] : 0;
    #pragma unroll
    for(int off=1; off<16; off<<=1){
      int y = __shfl_up(s2, off, 64);
      if(lane >= off) s2 += y;
    }
    if(lane<16) wsum[lane]=s2;
  }
  __syncthreads();
  int run = (x - v) + (wid ? wsum[wid-1] : 0);      // exclusive local start
  int g = v ? atomicAdd(&bfill[t], v) : 0;          // reserve in bucket region
  hist[t]=run; delta[t]= t*CCAP + g - run;          // hist becomes fill counter
  __syncthreads();
  // C: place into LDS sorted by bucket
  #pragma unroll
  for(int i=0;i<CHUNK;i+=1024){
    int e = cbase+i+t;
    if(e<E){
      int d = dst[e];
      int b = d>>7;
      int slot = atomicAdd(&hist[b], 1);
      vals[slot] = ((d&127)<<17) | src[e];
      bkt[slot]  = (unsigned short)b;
    }
  }
  __syncthreads();
  // D: dense copy-out (addresses consecutive within each run)
  int cnt = E - cbase; if(cnt > CHUNK) cnt = CHUNK;
  for(int i=t;i<cnt;i+=1024){
    int b = bkt[i];
    pairs[delta[b] + i] = vals[i];
  }
}

// One block per bucket (128 dst nodes). LDS counting sort -> rowse {s,e},
// dinv, srcs staged in LDS -> fully-contiguous col writes. R24: each node's
// segment is then insertion-sorted by src id (1 thread/node) so concurrent
// agg waves sweep the g-table in near-lockstep (L2 locality).
__global__ __launch_bounds__(256) void bucket_csr_kernel(const int* __restrict__ pairs,
                                                         const int* __restrict__ bfill,
                                                         int2* __restrict__ rowse,
                                                         float* __restrict__ dinv,
                                                         int* __restrict__ col,
                                                         int N){
  __shared__ int hist[128];
  __shared__ int pref[128];
  __shared__ int fill[128];
  __shared__ int srcs[CCAP];
  int b = blockIdx.x, t = threadIdx.x;
  int s0 = b*CCAP;
  int cnt = bfill[b]; if(cnt > CCAP) cnt = CCAP;   // unreachable guard
  if(t<128) hist[t]=0;
  __syncthreads();
  int v[CCAP/256];
  #pragma unroll
  for(int i=0;i<CCAP/256;i++){
    int idx = i*256 + t;
    if(idx<cnt){ v[i]=pairs[s0+idx]; atomicAdd(&hist[v[i]>>17], 1); }
  }
  __syncthreads();
  if(t<128) pref[t]=hist[t];
  __syncthreads();
  for(int off=1; off<128; off<<=1){
    int x=0;
    if(t<128 && t>=off) x=pref[t-off];
    __syncthreads();
    if(t<128) pref[t]+=x;
    __syncthreads();
  }
  if(t<128){
    int ex = pref[t]-hist[t];                 // exclusive prefix
    fill[t]=ex;
    int node = b*128 + t;
    if(node<N){
      rowse[node] = make_int2(s0+ex, s0+ex+hist[t]);
      dinv[node] = rsqrtf((float)(hist[t]+1)); // +1 self loop
    }
  }
  __syncthreads();
  #pragma unroll
  for(int i=0;i<CCAP/256;i++){
    int idx = i*256 + t;
    if(idx<cnt){
      int ld = v[i]>>17;
      int pos = atomicAdd(&fill[ld], 1);
      srcs[pos] = v[i] & 0x1FFFF;
    }
  }
  __syncthreads();
  // R24: per-node insertion sort of srcs segment (thread t owns node t).
  if(t<128){
    int s1 = pref[t]-hist[t], e1 = pref[t];
    for(int i=s1+1;i<e1;i++){
      int key = srcs[i], j=i-1;
      while(j>=s1 && srcs[j]>key){ srcs[j+1]=srcs[j]; j--; }
      srcs[j+1]=key;
    }
  }
  __syncthreads();
  for(int i=t;i<cnt;i+=256) col[s0+i]=srcs[i];   // contiguous
}

// g[n,:] = bf16( dinv[n] * (x[n,:128] @ W1[128,64]) ) via MFMA 16x16x32 bf16.
// Block = 64 rows (4 waves x 16 rows), 16 MFMAs/wave (4 ksteps x 4 nblocks).
// A-frags from global (lane l: row l&15, k-octet 8*(l>>4)); B-frags from LDS.
__global__ __launch_bounds__(256) void lin_mfma_kernel(const float* __restrict__ x,
                                                       const unsigned short* __restrict__ wf,
                                                       const float* __restrict__ dinv,
                                                       unsigned short* __restrict__ g,
                                                       int N){
  __shared__ __align__(16) unsigned short wl[4*4*64*8];   // 16KB
  int t = threadIdx.x, wave = t>>6, lane = t&63;
  #pragma unroll
  for(int idx=t; idx<1024; idx+=256)
    ((v4f*)wl)[idx] = ((const v4f*)wf)[idx];              // 16B per entry
  __syncthreads();
  int row = blockIdx.x*64 + wave*16 + (lane&15);
  int arow = row < N ? row : N-1;
  const float* xr = x + (size_t)arow*128 + 8*(lane>>4);
  f32x4 acc0={0.f,0.f,0.f,0.f}, acc1=acc0, acc2=acc0, acc3=acc0;
  #pragma unroll
  for(int ks=0; ks<4; ks++){
    v4f a0 = *(const v4f*)(xr + ks*32);
    v4f a1 = *(const v4f*)(xr + ks*32 + 4);
    short8 af;
    af[0]=(short)f32_to_bf16(a0.x); af[1]=(short)f32_to_bf16(a0.y);
    af[2]=(short)f32_to_bf16(a0.z); af[3]=(short)f32_to_bf16(a0.w);
    af[4]=(short)f32_to_bf16(a1.x); af[5]=(short)f32_to_bf16(a1.y);
    af[6]=(short)f32_to_bf16(a1.z); af[7]=(short)f32_to_bf16(a1.w);
    const short8* wb = ((const short8*)wl) + ks*256 + lane;
    acc0 = __builtin_amdgcn_mfma_f32_16x16x32_bf16(af, wb[0],   acc0, 0, 0, 0);
    acc1 = __builtin_amdgcn_mfma_f32_16x16x32_bf16(af, wb[64],  acc1, 0, 0, 0);
    acc2 = __builtin_amdgcn_mfma_f32_16x16x32_bf16(af, wb[128], acc2, 0, 0, 0);
    acc3 = __builtin_amdgcn_mfma_f32_16x16x32_bf16(af, wb[192], acc3, 0, 0, 0);
  }
  // C layout (m89-verified): col = lane&15, row = (lane>>4)*4 + j.
  int rbase = blockIdx.x*64 + wave*16 + (lane>>4)*4;
  int c = lane & 15;
  #pragma unroll
  for(int j=0;j<4;j++){
    int r = rbase + j;
    if(r < N){
      float dv = dinv[r];
      unsigned short* go = g + (size_t)r*64 + c;
      go[0]  = f32_to_bf16(dv*acc0[j]);
      go[16] = f32_to_bf16(dv*acc1[j]);
      go[32] = f32_to_bf16(dv*acc2[j]);
      go[48] = f32_to_bf16(dv*acc3[j]);
    }
  }
}

// Gather for 4-nodes-per-wave layout over bf16 g rows (128B each):
// lane = 16*q + l; group q handles node n, lane carries features [4l,4l+4).
// 4-granular early break (group-uniform); OOB slots clamp to zeroed row
// g[ZR]; v4f vector accumulate -> v_pk_add_f32. (R20-proven form.)
__device__ __forceinline__ v4f gather_row4(const unsigned short* __restrict__ g,
                                           const int* __restrict__ col,
                                           int n, int s, int e, int l, int ZR){
  v4f acc = bf16x4_to_f32(*(const v4u16*)&g[(size_t)n*64 + l*4]);   // self
  for(int i = s; i < e; i += 16){
    int rem = e - i;                               // group-uniform
    int myc = (l < rem) ? col[i + l] : ZR;
    #pragma unroll
    for(int j0 = 0; j0 < 16; j0 += 4){
      int c0 = __shfl(myc, j0+0, 16);
      int c1 = __shfl(myc, j0+1, 16);
      int c2 = __shfl(myc, j0+2, 16);
      int c3 = __shfl(myc, j0+3, 16);
      v4f x0 = bf16x4_to_f32(*(const v4u16*)&g[(size_t)c0*64 + l*4]);
      v4f x1 = bf16x4_to_f32(*(const v4u16*)&g[(size_t)c1*64 + l*4]);
      v4f x2 = bf16x4_to_f32(*(const v4u16*)&g[(size_t)c2*64 + l*4]);
      v4f x3 = bf16x4_to_f32(*(const v4u16*)&g[(size_t)c3*64 + l*4]);
      acc = acc + ((x0 + x1) + (x2 + x3));         // pk_add; same association
      if(j0+4 >= rem) break;                       // group-uniform early out
    }
  }
  return acc;
}

// Fused agg + next-layer linear. h = relu(dinv*gather + b) -> bf16 rows in
// LDS (144B pitch), then h[16x64] @ W[64x64] via 8 MFMAs (2/wave):
// wave = output col-block nb; A-frag: lane l reads row l&15, k-octet
// 8*(l>>4) (ds_read_b128, 16B-aligned, bank-stride 4 -> 2-way free).
__global__ __launch_bounds__(256) void agg_lin_kernel(const unsigned short* __restrict__ g,
                                                      const int2* __restrict__ rowse,
                                                      const int* __restrict__ col,
                                                      const float* __restrict__ dinv,
                                                      const float* __restrict__ bias,
                                                      const unsigned short* __restrict__ wf,
                                                      unsigned short* __restrict__ g2,
                                                      int N){
  __shared__ __align__(16) unsigned short hsh[16*72];     // 2.25KB padded bf16 h
  __shared__ __align__(16) unsigned short wl[2*4*64*8];   // 8KB W frags
  int t = threadIdx.x, wave = t>>6, lane = t&63;
  int l = lane & 15, q = lane >> 4;
  // stage W frags once per block: 512 x 16B, coalesced
  #pragma unroll
  for(int idx = t; idx < 512; idx += 256)
    ((v4f*)wl)[idx] = ((const v4f*)wf)[idx];
  int base = blockIdx.x*16;
  int n = base + wave*4 + q;
  bool valid = n < N;
  int nn = valid ? n : (N-1);
  int2 se = rowse[nn];
  v4f acc = gather_row4(g, col, nn, se.x, se.y, l, N);
  float dv = dinv[nn];
  v4f bs = *(const v4f*)&bias[l*4];
  v4u16 hb;
  hb.x = f32_to_bf16(fmaxf(fmaf(dv, acc.x, bs.x), 0.f));
  hb.y = f32_to_bf16(fmaxf(fmaf(dv, acc.y, bs.y), 0.f));
  hb.z = f32_to_bf16(fmaxf(fmaf(dv, acc.z, bs.z), 0.f));
  hb.w = f32_to_bf16(fmaxf(fmaf(dv, acc.w, bs.w), 0.f));
  *(v4u16*)&hsh[(wave*4+q)*72 + l*4] = hb;
  __syncthreads();
  // ---- h @ W via MFMA; this wave handles col-block nb = wave ----
  short8 a0 = *(const short8*)&hsh[(lane&15)*72 +      8*(lane>>4)];
  short8 a1 = *(const short8*)&hsh[(lane&15)*72 + 32 + 8*(lane>>4)];
  const short8* wb = ((const short8*)wl) + wave*64 + lane;
  f32x4 oc = {0.f,0.f,0.f,0.f};
  oc = __builtin_amdgcn_mfma_f32_16x16x32_bf16(a0, wb[0],   oc, 0, 0, 0);
  oc = __builtin_amdgcn_mfma_f32_16x16x32_bf16(a1, wb[256], oc, 0, 0, 0);
  // C layout: col = lane&15, row = (lane>>4)*4 + j
  int c  = wave*16 + (lane&15);
  int r0 = base + (lane>>4)*4;
  #pragma unroll
  for(int j=0;j<4;j++){
    int r = r0 + j;
    if(r < N)
      g2[(size_t)r*64 + c] = f32_to_bf16(dinv[r]*oc[j]);
  }
}

// Layer-3 agg with fused FC + log_softmax epilogue: never materializes h3.
__global__ __launch_bounds__(256) void agg_final_kernel(const unsigned short* __restrict__ g,
                                                        const int2* __restrict__ rowse,
                                                        const int* __restrict__ col,
                                                        const float* __restrict__ dinv,
                                                        const float* __restrict__ bias,
                                                        const float* __restrict__ Wfc,
                                                        const float* __restrict__ bfc,
                                                        float* __restrict__ out, int N){
  int t = threadIdx.x, wave = t>>6, lane = t&63;
  int l = lane & 15, q = lane >> 4;
  int n = blockIdx.x*16 + wave*4 + q;
  bool valid = n < N;
  if(!valid) n = N-1;
  int2 se = rowse[n];
  v4f acc = gather_row4(g, col, n, se.x, se.y, l, N);
  float dv = dinv[n];
  v4f bs = *(const v4f*)&bias[l*4];
  v4f hv;
  hv.x = fmaxf(fmaf(dv, acc.x, bs.x), 0.f);
  hv.y = fmaxf(fmaf(dv, acc.y, bs.y), 0.f);
  hv.z = fmaxf(fmaf(dv, acc.z, bs.z), 0.f);
  hv.w = fmaxf(fmaf(dv, acc.w, bs.w), 0.f);
  // Wfc row-major [64][2]: lane l covers features 4l..4l+3 -> 8 floats at 8l.
  v4f wa = *(const v4f*)&Wfc[l*8];
  v4f wb = *(const v4f*)&Wfc[l*8+4];
  float p0 = hv.x*wa.x + hv.y*wa.z + hv.z*wb.x + hv.w*wb.z;
  float p1 = hv.x*wa.y + hv.y*wa.w + hv.z*wb.y + hv.w*wb.w;
  for(int off=8; off; off>>=1){
    p0 += __shfl_down(p0, off, 16);
    p1 += __shfl_down(p1, off, 16);
  }
  if(valid && l==0){
    float l0 = p0 + bfc[0], l1 = p1 + bfc[1];
    float m  = fmaxf(l0, l1);
    float lse = m + logf(expf(l0-m) + expf(l1-m));
    out[(size_t)n*2+0] = l0 - lse;
    out[(size_t)n*2+1] = l1 - lse;
  }
}

extern "C" void kernel_launch(void* const* d_in, const int* in_sizes, int n_in,
                              void* d_out, int out_size, void* d_ws, size_t ws_size,
                              hipStream_t stream) {
  (void)n_in; (void)out_size; (void)ws_size;
  const float* x   = (const float*)d_in[0];
  const int*   ei  = (const int*)  d_in[1];
  const float* W1  = (const float*)d_in[2];
  const float* b1  = (const float*)d_in[3];
  const float* W2  = (const float*)d_in[4];
  const float* b2  = (const float*)d_in[5];
  const float* W3  = (const float*)d_in[6];
  const float* b3  = (const float*)d_in[7];
  const float* Wfc = (const float*)d_in[8];
  const float* bfc = (const float*)d_in[9];
  float* out = (float*)d_out;

  const int N = in_sizes[0] / 128;   // 100000
  const int E = in_sizes[1] / 2;     // 1600000
  const int* src = ei;
  const int* dst = ei + E;
  const int NB = (N + 127) / 128;    // 782 buckets

  // ---- workspace carve ----
  char* w = (char*)d_ws;
  int*   bfill   = (int*)  w; w += alignup((size_t)NBUCK*4);
  int*   pairs   = (int*)  w; w += alignup((size_t)NBUCK*CCAP*4);   // 14.7MB strided
  int2*  rowse   = (int2*) w; w += alignup((size_t)N*8);
  float* dinv    = (float*)w; w += alignup((size_t)N*4);
  int*   col     = (int*)  w; w += alignup((size_t)NBUCK*CCAP*4);   // 14.7MB strided
  unsigned short* gA = (unsigned short*)w; w += alignup((size_t)(N+1)*64*2); // bf16 (+zero row)
  unsigned short* gB = (unsigned short*)w; w += alignup((size_t)(N+1)*64*2); // bf16 (+zero row)
  unsigned short* wf1 = (unsigned short*)w; w += alignup((size_t)4*4*64*8*2); // W1 frags 16KB
  unsigned short* wf2 = (unsigned short*)w; w += alignup((size_t)2*4*64*8*2); // W2 frags 8KB
  unsigned short* wf3 = (unsigned short*)w; w += alignup((size_t)2*4*64*8*2); // W3 frags 8KB

  const int nblkE   = (E + CHUNK - 1) / CHUNK;   // 196
  const int nblkLin = (N + 63) / 64;             // 64 rows per MFMA block
  const int nblkAgg = (N + 15) / 16;             // 4 nodes/wave, 4 waves/blk

  // ---- setup (one kernel): W frags + bfill zero + g zero-rows ----
  setup_kernel<<<8, 256, 0, stream>>>(W1, W2, W3, wf1, wf2, wf3, bfill,
                                      gA + (size_t)N*64, gB + (size_t)N*64);
  // ---- CSR build: scatter into fixed-stride buckets, then per-bucket sort ----
  scatter_kernel<<<nblkE, 1024, 0, stream>>>(src, dst, bfill, pairs, E);
  bucket_csr_kernel<<<NB, 256, 0, stream>>>(pairs, bfill, rowse, dinv, col, N);

  // ---- layer 1 linear via MFMA: x[N,128] -> gA ----
  lin_mfma_kernel<<<nblkLin, 256, 0, stream>>>(x, wf1, dinv, gA, N);
  // ---- agg1 + lin2 fused (MFMA epilogue): gA -> gB ----
  agg_lin_kernel<<<nblkAgg, 256, 0, stream>>>(gA, rowse, col, dinv, b1, wf2, gB, N);
  // ---- agg2 + lin3 fused (MFMA epilogue): gB -> gA ----
  agg_lin_kernel<<<nblkAgg, 256, 0, stream>>>(gB, rowse, col, dinv, b2, wf3, gA, N);
  // ---- agg3 + FC + log_softmax (fused): gA -> out ----
  agg_final_kernel<<<nblkAgg, 256, 0, stream>>>(gA, rowse, col, dinv, b3,
                                                Wfc, bfc, out, N);
}

// Round 11
// 235.600 us; speedup vs baseline: 1.3844x; 1.1834x over previous
//
#include <hip/hip_runtime.h>
#include <math.h>

// ---------------------------------------------------------------------------
// FraudDetectionGCN: 3x GCNConv(relu) + FC + log_softmax.
// R25 = R20 byte-identical restore (best: 233.6 us). R24's per-node neighbor
// sort cost +35us in bucket_csr (serial insertion sort, 1.68M LDS conflicts)
// with zero agg gain -> random graph has no exploitable inter-edge locality.
// Conclusion of R19-R24 arc: the agg gather is at its memory-service
// roofline (~2 TB/s L2-miss service on random 128B rows; FETCH ~ 83MB is
// graph-determined: 12.8MB g-table vs 4MB per-XCD L2, random reuse).
// Components: CSR = 2 edge passes (minimum); lin = MFMA; agg epilogues =
// MFMA; agg gather = memory-service-bound.
// agg: bf16 g rows; norm factorization:
// out[n] = dinv[n]*(sum_{s->n} g[s] + g[n]) + b, g = dinv[:,None]*(h@W).
// ---------------------------------------------------------------------------

static inline size_t alignup(size_t x){ return (x + 511) & ~size_t(511); }

typedef float v4f __attribute__((ext_vector_type(4)));
typedef unsigned short v4u16 __attribute__((ext_vector_type(4)));
typedef __attribute__((ext_vector_type(8))) short short8;   // MFMA A/B frag (8 bf16)
typedef __attribute__((ext_vector_type(4))) float f32x4;    // MFMA C/D frag

__device__ __forceinline__ unsigned short f32_to_bf16(float f){
  union { float f; unsigned int u; } c; c.f = f;
  unsigned int u = c.u + 0x7FFFu + ((c.u >> 16) & 1u);   // round-nearest-even
  return (unsigned short)(u >> 16);
}
__device__ __forceinline__ v4f bf16x4_to_f32(v4u16 a){
  union { unsigned int u; float f; } c0,c1,c2,c3;
  c0.u = (unsigned int)a.x << 16;
  c1.u = (unsigned int)a.y << 16;
  c2.u = (unsigned int)a.z << 16;
  c3.u = (unsigned int)a.w << 16;
  v4f r; r.x=c0.f; r.y=c1.f; r.z=c2.f; r.w=c3.f;
  return r;
}

#define NBUCK 1024          // histogram bins (dst>>7); 782 used at N=100k
#define CHUNK 8192          // edges per block in scatter (196 blocks)
#define CCAP  3584          // bucket region stride (mean ~2046, +34 sigma)

// Build one bf16 MFMA B-fragment entry for W[ksteps*32][64]:
// wf[ks][nb][lane][i] = bf16( W[ks*32 + 8*(lane>>4) + i][nb*16 + (lane&15)] ).
__device__ __forceinline__ void wfrag_one(const float* __restrict__ W,
                                          unsigned short* __restrict__ wf,
                                          int idx, int ksteps){
  int total = ksteps*4*64;
  if(idx >= total) return;
  int l  = idx & 63;
  int nb = (idx>>6) & 3;
  int ks = idx>>8;
  int k0 = ks*32 + 8*(l>>4);
  int n  = nb*16 + (l&15);
  unsigned short* o = wf + (size_t)idx*8;
  #pragma unroll
  for(int i=0;i<8;i++) o[i] = f32_to_bf16(W[(size_t)(k0+i)*64 + n]);
}

// One-shot setup: W1/W2/W3 fragments, zero bfill, zero g zero-rows. 8 blocks.
__global__ __launch_bounds__(256) void setup_kernel(const float* __restrict__ W1,
                                                    const float* __restrict__ W2,
                                                    const float* __restrict__ W3,
                                                    unsigned short* __restrict__ wf1,
                                                    unsigned short* __restrict__ wf2,
                                                    unsigned short* __restrict__ wf3,
                                                    int* __restrict__ bfill,
                                                    unsigned short* __restrict__ gAz,
                                                    unsigned short* __restrict__ gBz){
  int b = blockIdx.x, t = threadIdx.x;
  if(b < 4)      wfrag_one(W1, wf1, b*256+t, 4);
  else if(b < 6) wfrag_one(W2, wf2, (b-4)*256+t, 2);
  else           wfrag_one(W3, wf3, (b-6)*256+t, 2);
  if(b < 4) bfill[b*256+t] = 0;                 // 1024 bucket counters
  if(b==4 && t<32) ((int*)gAz)[t] = 0;          // zero row (64 bf16 = 32 ints)
  if(b==5 && t<32) ((int*)gBz)[t] = 0;
}

// Scatter packed (local_dst<<17 | src) into fixed-stride bucket regions,
// LDS-presorted so global writes are dense runs. 1024 threads (16 waves).
// Bucket base is b*CCAP (compile-time stride): no hist/scan passes needed.
__global__ __launch_bounds__(1024) void scatter_kernel(const int* __restrict__ src,
                                                       const int* __restrict__ dst,
                                                       int* __restrict__ bfill,
                                                       int* __restrict__ pairs, int E){
  __shared__ int hist[NBUCK];            // counts -> reused as fill counters
  __shared__ int delta[NBUCK];           // gstart - lstart per bucket
  __shared__ int wsum[16];
  __shared__ int vals[CHUNK];            // 32KB sorted-by-bucket payloads
  __shared__ unsigned short bkt[CHUNK];  // 16KB bucket id per slot
  int t = threadIdx.x;
  int lane = t & 63, wid = t >> 6;
  int cbase = blockIdx.x*CHUNK;
  hist[t]=0;                             // NBUCK == 1024
  __syncthreads();
  // A: local histogram
  #pragma unroll
  for(int i=0;i<CHUNK;i+=1024){
    int e = cbase+i+t;
    if(e<E) atomicAdd(&hist[dst[e]>>7], 1);
  }
  __syncthreads();
  // B: block-exclusive scan (1 bucket/thread): wave shfl scan + combine
  int v = hist[t];
  int x = v;
  #pragma unroll
  for(int off=1; off<64; off<<=1){
    int y = __shfl_up(x, off, 64);
    if(lane >= off) x += y;
  }
  if(lane==63) wsum[wid]=x;
  __syncthreads();
  if(wid==0){
    int s2 = (lane<16) ? wsum[lane] : 0;
    #pragma unroll
    for(int off=1; off<16; off<<=1){
      int y = __shfl_up(s2, off, 64);
      if(lane >= off) s2 += y;
    }
    if(lane<16) wsum[lane]=s2;
  }
  __syncthreads();
  int run = (x - v) + (wid ? wsum[wid-1] : 0);      // exclusive local start
  int g = v ? atomicAdd(&bfill[t], v) : 0;          // reserve in bucket region
  hist[t]=run; delta[t]= t*CCAP + g - run;          // hist becomes fill counter
  __syncthreads();
  // C: place into LDS sorted by bucket
  #pragma unroll
  for(int i=0;i<CHUNK;i+=1024){
    int e = cbase+i+t;
    if(e<E){
      int d = dst[e];
      int b = d>>7;
      int slot = atomicAdd(&hist[b], 1);
      vals[slot] = ((d&127)<<17) | src[e];
      bkt[slot]  = (unsigned short)b;
    }
  }
  __syncthreads();
  // D: dense copy-out (addresses consecutive within each run)
  int cnt = E - cbase; if(cnt > CHUNK) cnt = CHUNK;
  for(int i=t;i<cnt;i+=1024){
    int b = bkt[i];
    pairs[delta[b] + i] = vals[i];
  }
}

// One block per bucket (128 dst nodes). LDS counting sort -> rowse {s,e},
// dinv, srcs staged in LDS -> fully-contiguous col writes. (R20 form.)
__global__ __launch_bounds__(256) void bucket_csr_kernel(const int* __restrict__ pairs,
                                                         const int* __restrict__ bfill,
                                                         int2* __restrict__ rowse,
                                                         float* __restrict__ dinv,
                                                         int* __restrict__ col,
                                                         int N){
  __shared__ int hist[128];
  __shared__ int pref[128];
  __shared__ int fill[128];
  __shared__ int srcs[CCAP];
  int b = blockIdx.x, t = threadIdx.x;
  int s0 = b*CCAP;
  int cnt = bfill[b]; if(cnt > CCAP) cnt = CCAP;   // unreachable guard
  if(t<128) hist[t]=0;
  __syncthreads();
  int v[CCAP/256];
  #pragma unroll
  for(int i=0;i<CCAP/256;i++){
    int idx = i*256 + t;
    if(idx<cnt){ v[i]=pairs[s0+idx]; atomicAdd(&hist[v[i]>>17], 1); }
  }
  __syncthreads();
  if(t<128) pref[t]=hist[t];
  __syncthreads();
  for(int off=1; off<128; off<<=1){
    int x=0;
    if(t<128 && t>=off) x=pref[t-off];
    __syncthreads();
    if(t<128) pref[t]+=x;
    __syncthreads();
  }
  if(t<128){
    int ex = pref[t]-hist[t];                 // exclusive prefix
    fill[t]=ex;
    int node = b*128 + t;
    if(node<N){
      rowse[node] = make_int2(s0+ex, s0+ex+hist[t]);
      dinv[node] = rsqrtf((float)(hist[t]+1)); // +1 self loop
    }
  }
  __syncthreads();
  #pragma unroll
  for(int i=0;i<CCAP/256;i++){
    int idx = i*256 + t;
    if(idx<cnt){
      int ld = v[i]>>17;
      int pos = atomicAdd(&fill[ld], 1);
      srcs[pos] = v[i] & 0x1FFFF;
    }
  }
  __syncthreads();
  for(int i=t;i<cnt;i+=256) col[s0+i]=srcs[i];   // contiguous
}

// g[n,:] = bf16( dinv[n] * (x[n,:128] @ W1[128,64]) ) via MFMA 16x16x32 bf16.
// Block = 64 rows (4 waves x 16 rows), 16 MFMAs/wave (4 ksteps x 4 nblocks).
// A-frags from global (lane l: row l&15, k-octet 8*(l>>4)); B-frags from LDS.
__global__ __launch_bounds__(256) void lin_mfma_kernel(const float* __restrict__ x,
                                                       const unsigned short* __restrict__ wf,
                                                       const float* __restrict__ dinv,
                                                       unsigned short* __restrict__ g,
                                                       int N){
  __shared__ __align__(16) unsigned short wl[4*4*64*8];   // 16KB
  int t = threadIdx.x, wave = t>>6, lane = t&63;
  #pragma unroll
  for(int idx=t; idx<1024; idx+=256)
    ((v4f*)wl)[idx] = ((const v4f*)wf)[idx];              // 16B per entry
  __syncthreads();
  int row = blockIdx.x*64 + wave*16 + (lane&15);
  int arow = row < N ? row : N-1;
  const float* xr = x + (size_t)arow*128 + 8*(lane>>4);
  f32x4 acc0={0.f,0.f,0.f,0.f}, acc1=acc0, acc2=acc0, acc3=acc0;
  #pragma unroll
  for(int ks=0; ks<4; ks++){
    v4f a0 = *(const v4f*)(xr + ks*32);
    v4f a1 = *(const v4f*)(xr + ks*32 + 4);
    short8 af;
    af[0]=(short)f32_to_bf16(a0.x); af[1]=(short)f32_to_bf16(a0.y);
    af[2]=(short)f32_to_bf16(a0.z); af[3]=(short)f32_to_bf16(a0.w);
    af[4]=(short)f32_to_bf16(a1.x); af[5]=(short)f32_to_bf16(a1.y);
    af[6]=(short)f32_to_bf16(a1.z); af[7]=(short)f32_to_bf16(a1.w);
    const short8* wb = ((const short8*)wl) + ks*256 + lane;
    acc0 = __builtin_amdgcn_mfma_f32_16x16x32_bf16(af, wb[0],   acc0, 0, 0, 0);
    acc1 = __builtin_amdgcn_mfma_f32_16x16x32_bf16(af, wb[64],  acc1, 0, 0, 0);
    acc2 = __builtin_amdgcn_mfma_f32_16x16x32_bf16(af, wb[128], acc2, 0, 0, 0);
    acc3 = __builtin_amdgcn_mfma_f32_16x16x32_bf16(af, wb[192], acc3, 0, 0, 0);
  }
  // C layout (m89-verified): col = lane&15, row = (lane>>4)*4 + j.
  int rbase = blockIdx.x*64 + wave*16 + (lane>>4)*4;
  int c = lane & 15;
  #pragma unroll
  for(int j=0;j<4;j++){
    int r = rbase + j;
    if(r < N){
      float dv = dinv[r];
      unsigned short* go = g + (size_t)r*64 + c;
      go[0]  = f32_to_bf16(dv*acc0[j]);
      go[16] = f32_to_bf16(dv*acc1[j]);
      go[32] = f32_to_bf16(dv*acc2[j]);
      go[48] = f32_to_bf16(dv*acc3[j]);
    }
  }
}

// Gather for 4-nodes-per-wave layout over bf16 g rows (128B each):
// lane = 16*q + l; group q handles node n, lane carries features [4l,4l+4).
// 4-granular early break (group-uniform); OOB slots clamp to zeroed row
// g[ZR]; v4f vector accumulate -> v_pk_add_f32. (R20-proven form.)
__device__ __forceinline__ v4f gather_row4(const unsigned short* __restrict__ g,
                                           const int* __restrict__ col,
                                           int n, int s, int e, int l, int ZR){
  v4f acc = bf16x4_to_f32(*(const v4u16*)&g[(size_t)n*64 + l*4]);   // self
  for(int i = s; i < e; i += 16){
    int rem = e - i;                               // group-uniform
    int myc = (l < rem) ? col[i + l] : ZR;
    #pragma unroll
    for(int j0 = 0; j0 < 16; j0 += 4){
      int c0 = __shfl(myc, j0+0, 16);
      int c1 = __shfl(myc, j0+1, 16);
      int c2 = __shfl(myc, j0+2, 16);
      int c3 = __shfl(myc, j0+3, 16);
      v4f x0 = bf16x4_to_f32(*(const v4u16*)&g[(size_t)c0*64 + l*4]);
      v4f x1 = bf16x4_to_f32(*(const v4u16*)&g[(size_t)c1*64 + l*4]);
      v4f x2 = bf16x4_to_f32(*(const v4u16*)&g[(size_t)c2*64 + l*4]);
      v4f x3 = bf16x4_to_f32(*(const v4u16*)&g[(size_t)c3*64 + l*4]);
      acc = acc + ((x0 + x1) + (x2 + x3));         // pk_add; same association
      if(j0+4 >= rem) break;                       // group-uniform early out
    }
  }
  return acc;
}

// Fused agg + next-layer linear. h = relu(dinv*gather + b) -> bf16 rows in
// LDS (144B pitch), then h[16x64] @ W[64x64] via 8 MFMAs (2/wave):
// wave = output col-block nb; A-frag: lane l reads row l&15, k-octet
// 8*(l>>4) (ds_read_b128, 16B-aligned, bank-stride 4 -> 2-way free).
__global__ __launch_bounds__(256) void agg_lin_kernel(const unsigned short* __restrict__ g,
                                                      const int2* __restrict__ rowse,
                                                      const int* __restrict__ col,
                                                      const float* __restrict__ dinv,
                                                      const float* __restrict__ bias,
                                                      const unsigned short* __restrict__ wf,
                                                      unsigned short* __restrict__ g2,
                                                      int N){
  __shared__ __align__(16) unsigned short hsh[16*72];     // 2.25KB padded bf16 h
  __shared__ __align__(16) unsigned short wl[2*4*64*8];   // 8KB W frags
  int t = threadIdx.x, wave = t>>6, lane = t&63;
  int l = lane & 15, q = lane >> 4;
  // stage W frags once per block: 512 x 16B, coalesced
  #pragma unroll
  for(int idx = t; idx < 512; idx += 256)
    ((v4f*)wl)[idx] = ((const v4f*)wf)[idx];
  int base = blockIdx.x*16;
  int n = base + wave*4 + q;
  bool valid = n < N;
  int nn = valid ? n : (N-1);
  int2 se = rowse[nn];
  v4f acc = gather_row4(g, col, nn, se.x, se.y, l, N);
  float dv = dinv[nn];
  v4f bs = *(const v4f*)&bias[l*4];
  v4u16 hb;
  hb.x = f32_to_bf16(fmaxf(fmaf(dv, acc.x, bs.x), 0.f));
  hb.y = f32_to_bf16(fmaxf(fmaf(dv, acc.y, bs.y), 0.f));
  hb.z = f32_to_bf16(fmaxf(fmaf(dv, acc.z, bs.z), 0.f));
  hb.w = f32_to_bf16(fmaxf(fmaf(dv, acc.w, bs.w), 0.f));
  *(v4u16*)&hsh[(wave*4+q)*72 + l*4] = hb;
  __syncthreads();
  // ---- h @ W via MFMA; this wave handles col-block nb = wave ----
  short8 a0 = *(const short8*)&hsh[(lane&15)*72 +      8*(lane>>4)];
  short8 a1 = *(const short8*)&hsh[(lane&15)*72 + 32 + 8*(lane>>4)];
  const short8* wb = ((const short8*)wl) + wave*64 + lane;
  f32x4 oc = {0.f,0.f,0.f,0.f};
  oc = __builtin_amdgcn_mfma_f32_16x16x32_bf16(a0, wb[0],   oc, 0, 0, 0);
  oc = __builtin_amdgcn_mfma_f32_16x16x32_bf16(a1, wb[256], oc, 0, 0, 0);
  // C layout: col = lane&15, row = (lane>>4)*4 + j
  int c  = wave*16 + (lane&15);
  int r0 = base + (lane>>4)*4;
  #pragma unroll
  for(int j=0;j<4;j++){
    int r = r0 + j;
    if(r < N)
      g2[(size_t)r*64 + c] = f32_to_bf16(dinv[r]*oc[j]);
  }
}

// Layer-3 agg with fused FC + log_softmax epilogue: never materializes h3.
__global__ __launch_bounds__(256) void agg_final_kernel(const unsigned short* __restrict__ g,
                                                        const int2* __restrict__ rowse,
                                                        const int* __restrict__ col,
                                                        const float* __restrict__ dinv,
                                                        const float* __restrict__ bias,
                                                        const float* __restrict__ Wfc,
                                                        const float* __restrict__ bfc,
                                                        float* __restrict__ out, int N){
  int t = threadIdx.x, wave = t>>6, lane = t&63;
  int l = lane & 15, q = lane >> 4;
  int n = blockIdx.x*16 + wave*4 + q;
  bool valid = n < N;
  if(!valid) n = N-1;
  int2 se = rowse[n];
  v4f acc = gather_row4(g, col, n, se.x, se.y, l, N);
  float dv = dinv[n];
  v4f bs = *(const v4f*)&bias[l*4];
  v4f hv;
  hv.x = fmaxf(fmaf(dv, acc.x, bs.x), 0.f);
  hv.y = fmaxf(fmaf(dv, acc.y, bs.y), 0.f);
  hv.z = fmaxf(fmaf(dv, acc.z, bs.z), 0.f);
  hv.w = fmaxf(fmaf(dv, acc.w, bs.w), 0.f);
  // Wfc row-major [64][2]: lane l covers features 4l..4l+3 -> 8 floats at 8l.
  v4f wa = *(const v4f*)&Wfc[l*8];
  v4f wb = *(const v4f*)&Wfc[l*8+4];
  float p0 = hv.x*wa.x + hv.y*wa.z + hv.z*wb.x + hv.w*wb.z;
  float p1 = hv.x*wa.y + hv.y*wa.w + hv.z*wb.y + hv.w*wb.w;
  for(int off=8; off; off>>=1){
    p0 += __shfl_down(p0, off, 16);
    p1 += __shfl_down(p1, off, 16);
  }
  if(valid && l==0){
    float l0 = p0 + bfc[0], l1 = p1 + bfc[1];
    float m  = fmaxf(l0, l1);
    float lse = m + logf(expf(l0-m) + expf(l1-m));
    out[(size_t)n*2+0] = l0 - lse;
    out[(size_t)n*2+1] = l1 - lse;
  }
}

extern "C" void kernel_launch(void* const* d_in, const int* in_sizes, int n_in,
                              void* d_out, int out_size, void* d_ws, size_t ws_size,
                              hipStream_t stream) {
  (void)n_in; (void)out_size; (void)ws_size;
  const float* x   = (const float*)d_in[0];
  const int*   ei  = (const int*)  d_in[1];
  const float* W1  = (const float*)d_in[2];
  const float* b1  = (const float*)d_in[3];
  const float* W2  = (const float*)d_in[4];
  const float* b2  = (const float*)d_in[5];
  const float* W3  = (const float*)d_in[6];
  const float* b3  = (const float*)d_in[7];
  const float* Wfc = (const float*)d_in[8];
  const float* bfc = (const float*)d_in[9];
  float* out = (float*)d_out;

  const int N = in_sizes[0] / 128;   // 100000
  const int E = in_sizes[1] / 2;     // 1600000
  const int* src = ei;
  const int* dst = ei + E;
  const int NB = (N + 127) / 128;    // 782 buckets

  // ---- workspace carve ----
  char* w = (char*)d_ws;
  int*   bfill   = (int*)  w; w += alignup((size_t)NBUCK*4);
  int*   pairs   = (int*)  w; w += alignup((size_t)NBUCK*CCAP*4);   // 14.7MB strided
  int2*  rowse   = (int2*) w; w += alignup((size_t)N*8);
  float* dinv    = (float*)w; w += alignup((size_t)N*4);
  int*   col     = (int*)  w; w += alignup((size_t)NBUCK*CCAP*4);   // 14.7MB strided
  unsigned short* gA = (unsigned short*)w; w += alignup((size_t)(N+1)*64*2); // bf16 (+zero row)
  unsigned short* gB = (unsigned short*)w; w += alignup((size_t)(N+1)*64*2); // bf16 (+zero row)
  unsigned short* wf1 = (unsigned short*)w; w += alignup((size_t)4*4*64*8*2); // W1 frags 16KB
  unsigned short* wf2 = (unsigned short*)w; w += alignup((size_t)2*4*64*8*2); // W2 frags 8KB
  unsigned short* wf3 = (unsigned short*)w; w += alignup((size_t)2*4*64*8*2); // W3 frags 8KB

  const int nblkE   = (E + CHUNK - 1) / CHUNK;   // 196
  const int nblkLin = (N + 63) / 64;             // 64 rows per MFMA block
  const int nblkAgg = (N + 15) / 16;             // 4 nodes/wave, 4 waves/blk

  // ---- setup (one kernel): W frags + bfill zero + g zero-rows ----
  setup_kernel<<<8, 256, 0, stream>>>(W1, W2, W3, wf1, wf2, wf3, bfill,
                                      gA + (size_t)N*64, gB + (size_t)N*64);
  // ---- CSR build: scatter into fixed-stride buckets, then per-bucket sort ----
  scatter_kernel<<<nblkE, 1024, 0, stream>>>(src, dst, bfill, pairs, E);
  bucket_csr_kernel<<<NB, 256, 0, stream>>>(pairs, bfill, rowse, dinv, col, N);

  // ---- layer 1 linear via MFMA: x[N,128] -> gA ----
  lin_mfma_kernel<<<nblkLin, 256, 0, stream>>>(x, wf1, dinv, gA, N);
  // ---- agg1 + lin2 fused (MFMA epilogue): gA -> gB ----
  agg_lin_kernel<<<nblkAgg, 256, 0, stream>>>(gA, rowse, col, dinv, b1, wf2, gB, N);
  // ---- agg2 + lin3 fused (MFMA epilogue): gB -> gA ----
  agg_lin_kernel<<<nblkAgg, 256, 0, stream>>>(gB, rowse, col, dinv, b2, wf3, gA, N);
  // ---- agg3 + FC + log_softmax (fused): gA -> out ----
  agg_final_kernel<<<nblkAgg, 256, 0, stream>>>(gA, rowse, col, dinv, b3,
                                                Wfc, bfc, out, N);
}